// Round 6
// baseline (124.541 us; speedup 1.0000x reference)
//
#include <hip/hip_runtime.h>
#include <hip/hip_bf16.h>
#include <math.h>

#define BB 2
#define HH 64
#define WW 64
#define CC 128
#define NH 4
#define HD 32
#define KK 7

typedef __attribute__((ext_vector_type(8))) short short8v;   // 8 bf16 = 4 VGPR
typedef __attribute__((ext_vector_type(4))) float float4v;

__device__ __forceinline__ unsigned short f2bf(float f) {
    union { float f; unsigned int u; } c; c.f = f;
    unsigned int r = c.u + 0x7FFFu + ((c.u >> 16) & 1u);  // RNE
    return (unsigned short)(r >> 16);
}

// ---------------------------------------------------------------------------
// K0: block 0: ada = silu(sinemb(t)) @ ln_w + ln_b
//     blocks 1..16: tiled 64x64 LDS transpose + bf16 cast of qkv_w / proj_w
// ---------------------------------------------------------------------------
__global__ __launch_bounds__(256) void k_prep(const int* __restrict__ t,
                                              const float* __restrict__ ln_w,
                                              const float* __restrict__ ln_b,
                                              const float* __restrict__ qkv_w,
                                              const float* __restrict__ proj_w,
                                              float* __restrict__ ada,
                                              unsigned short* __restrict__ wTq,
                                              unsigned short* __restrict__ wTp) {
    const int j = threadIdx.x;
    if (blockIdx.x == 0) {
        __shared__ float s_emb[CC];
        for (int b = 0; b < BB; ++b) {
            const float tf = (float)t[b] / 100.0f * 4000.0f;
            if (j < CC) {
                const int i = j & 63;
                const float freq = expf((float)i * (-logf(10000.0f) / 63.0f));
                const float e = tf * freq;
                const float em = (j < 64) ? sinf(e) : cosf(e);
                s_emb[j] = em / (1.0f + expf(-em));
            }
            __syncthreads();
            float acc = ln_b[j];
            #pragma unroll 4
            for (int c = 0; c < CC; ++c) acc += s_emb[c] * ln_w[c * 2 * CC + j];
            ada[b * 2 * CC + j] = acc;
            __syncthreads();
        }
        return;
    }
    // transpose tiles
    int tb = blockIdx.x - 1;
    const float* src; unsigned short* dst; int srcld, c0, n0;
    if (tb < 12) { src = qkv_w; dst = wTq; srcld = 384; c0 = (tb / 6) * 64; n0 = (tb % 6) * 64; }
    else { tb -= 12; src = proj_w; dst = wTp; srcld = 128; c0 = (tb >> 1) * 64; n0 = (tb & 1) * 64; }
    __shared__ float s[64][65];
    #pragma unroll
    for (int it = 0; it < 16; ++it) {
        const int idx = it * 256 + j;
        const int c = idx >> 6, n = idx & 63;
        s[c][n] = src[(size_t)(c0 + c) * srcld + n0 + n];
    }
    __syncthreads();
    #pragma unroll
    for (int it = 0; it < 16; ++it) {
        const int idx = it * 256 + j;
        const int n = idx >> 6, c = idx & 63;
        dst[(size_t)(n0 + n) * 128 + c0 + c] = f2bf(s[c][n]);
    }
}

// ---------------------------------------------------------------------------
// K1: LN + AdaLN + qkv GEMM via MFMA. 256 thr = 4 waves, 16 pixels/block.
// Wave wv owns output columns [wv*96, wv*96+96). B-frags in registers.
// q/k/v written [B][NH][HW][HD]; q pre-scaled by HD^-0.5.
// ---------------------------------------------------------------------------
__global__ __launch_bounds__(256) void k_lnqkv(const float* __restrict__ x,
                                               const float* __restrict__ ada,
                                               const unsigned short* __restrict__ wTq,
                                               const float* __restrict__ qkv_b,
                                               float* __restrict__ q,
                                               float* __restrict__ k,
                                               float* __restrict__ v) {
    const int tid = threadIdx.x;
    const int lane = tid & 63;
    const int wv = tid >> 6;
    const int pix0 = blockIdx.x * 16;
    const int b = pix0 >> 12;

    __shared__ unsigned short s_y[16 * 128];  // bf16 y tile, XOR-swizzled

    const int n0 = wv * 96;
    const int bn = n0 + (lane & 15);
    const int bk = (lane >> 4) * 8;
    short8v bfrag[24];
    #pragma unroll
    for (int nt = 0; nt < 6; ++nt)
        #pragma unroll
        for (int kk = 0; kk < 4; ++kk)
            bfrag[nt * 4 + kk] =
                *(const short8v*)(wTq + (size_t)(bn + nt * 16) * 128 + kk * 32 + bk);

    const int p = tid >> 4;
    const int c0 = (tid & 15) * 8;
    const float* xp = x + (size_t)(pix0 + p) * CC + c0;
    const float4v x0 = *(const float4v*)xp;
    const float4v x1 = *(const float4v*)(xp + 4);
    float s = 0.f, ss = 0.f;
    #pragma unroll
    for (int i = 0; i < 4; ++i) { s += x0[i]; ss += x0[i] * x0[i]; }
    #pragma unroll
    for (int i = 0; i < 4; ++i) { s += x1[i]; ss += x1[i] * x1[i]; }
    #pragma unroll
    for (int o = 8; o > 0; o >>= 1) {
        s  += __shfl_xor(s, o, 16);
        ss += __shfl_xor(ss, o, 16);
    }
    const float mean = s * (1.0f / CC);
    const float var  = ss * (1.0f / CC) - mean * mean;
    const float rstd = rsqrtf(var + 1e-5f);
    const float4v sc0 = *(const float4v*)(ada + b * 256 + c0);
    const float4v sc1 = *(const float4v*)(ada + b * 256 + c0 + 4);
    const float4v sh0 = *(const float4v*)(ada + b * 256 + 128 + c0);
    const float4v sh1 = *(const float4v*)(ada + b * 256 + 128 + c0 + 4);
    short8v ypack;
    #pragma unroll
    for (int i = 0; i < 4; ++i)
        ypack[i] = (short)f2bf((x0[i] - mean) * rstd * (1.0f + sc0[i]) + sh0[i]);
    #pragma unroll
    for (int i = 0; i < 4; ++i)
        ypack[4 + i] = (short)f2bf((x1[i] - mean) * rstd * (1.0f + sc1[i]) + sh1[i]);
    {
        int o = p * 256 + (tid & 15) * 16;
        o ^= (p & 7) << 4;                       // st-swizzle (T2)
        *(short8v*)((char*)s_y + o) = ypack;
    }
    __syncthreads();

    const int am = lane & 15;
    short8v afr[4];
    #pragma unroll
    for (int kk = 0; kk < 4; ++kk) {
        int o = am * 256 + kk * 64 + (lane >> 4) * 16;
        o ^= (am & 7) << 4;
        afr[kk] = *(const short8v*)((const char*)s_y + o);
    }

    float4v acc[6];
    #pragma unroll
    for (int nt = 0; nt < 6; ++nt) acc[nt] = (float4v){0.f, 0.f, 0.f, 0.f};
    #pragma unroll
    for (int nt = 0; nt < 6; ++nt)
        #pragma unroll
        for (int kk = 0; kk < 4; ++kk)
            acc[nt] = __builtin_amdgcn_mfma_f32_16x16x32_bf16(
                afr[kk], bfrag[nt * 4 + kk], acc[nt], 0, 0, 0);

    #pragma unroll
    for (int nt = 0; nt < 6; ++nt) {
        const int n = n0 + nt * 16 + (lane & 15);
        const float bias = qkv_b[n];
        const int which = n >> 7;               // 0=q 1=k 2=v
        const int head = (n & 127) >> 5;
        const int d = n & 31;
        float* base = (which == 0) ? q : (which == 1) ? k : v;
        #pragma unroll
        for (int jj = 0; jj < 4; ++jj) {
            const int pix = pix0 + (lane >> 4) * 4 + jj;
            const int hw = pix & 4095;
            float val = acc[nt][jj] + bias;
            if (which == 0) val *= 0.17677669529663687f;
            base[((size_t)(b * NH + head) * (HH * WW) + hw) * HD + d] = val;
        }
    }
}

// ---------------------------------------------------------------------------
// K2: neighborhood attention, 8 lanes per query (4 dims each).
// Three phases: (A) 49 independent score computations into a register array
// (loads pipeline), (B) max-tree + exp + sum (no online rescale chain),
// (C) 49 independent PV FMAs.
// ---------------------------------------------------------------------------
__global__ __launch_bounds__(256) void k_attn(const float* __restrict__ q,
                                              const float* __restrict__ k,
                                              const float* __restrict__ v,
                                              const float* __restrict__ rpb,
                                              float* __restrict__ attn_out) {
    const int gt = blockIdx.x * blockDim.x + threadIdx.x;
    const int query = gt >> 3;
    const int d0 = (gt & 7) * 4;
    const int w = query & 63;
    const int h = (query >> 6) & 63;
    const int n = (query >> 12) & 3;
    const int b = query >> 14;

    const float4 q4 = *(const float4*)(q + (size_t)query * HD + d0);

    const int hs = min(max(h - 3, 0), HH - KK);
    const int ws = min(max(w - 3, 0), WW - KK);
    const float* rp = rpb + n * 13 * 13 + (hs - h + 6) * 13 + (ws - w + 6);
    const size_t base0 = (((size_t)(b * NH + n) * HH + hs) * WW + ws) * HD + d0;

    // Phase A: scores
    float sc[49];
    #pragma unroll
    for (int a = 0; a < KK; ++a) {
        const float* kbase = k + base0 + (size_t)a * (WW * HD);
        #pragma unroll
        for (int c = 0; c < KK; ++c) {
            const float4 k4 = *(const float4*)(kbase + c * HD);
            float sdot = fmaf(q4.x, k4.x, fmaf(q4.y, k4.y, fmaf(q4.z, k4.z, q4.w * k4.w)));
            sdot += __shfl_xor(sdot, 4, 8);
            sdot += __shfl_xor(sdot, 2, 8);
            sdot += __shfl_xor(sdot, 1, 8);
            sc[a * KK + c] = sdot + rp[a * 13 + c];
        }
    }

    // Phase B: softmax over 49 (all 8 lanes hold identical copies)
    float m = sc[0];
    #pragma unroll
    for (int i = 1; i < 49; ++i) m = fmaxf(m, sc[i]);
    float l = 0.f;
    #pragma unroll
    for (int i = 0; i < 49; ++i) { sc[i] = __expf(sc[i] - m); l += sc[i]; }
    const float inv = 1.0f / l;

    // Phase C: PV
    float ax = 0.f, ay = 0.f, az = 0.f, aw = 0.f;
    #pragma unroll
    for (int a = 0; a < KK; ++a) {
        const float* vbase = v + base0 + (size_t)a * (WW * HD);
        #pragma unroll
        for (int c = 0; c < KK; ++c) {
            const float4 v4 = *(const float4*)(vbase + c * HD);
            const float pp = sc[a * KK + c];
            ax = fmaf(pp, v4.x, ax);
            ay = fmaf(pp, v4.y, ay);
            az = fmaf(pp, v4.z, az);
            aw = fmaf(pp, v4.w, aw);
        }
    }
    const int hw = query & 4095;
    float* op = attn_out + ((size_t)(b * (HH * WW) + hw)) * CC + n * HD + d0;
    op[0] = ax * inv; op[1] = ay * inv; op[2] = az * inv; op[3] = aw * inv;
}

// ---------------------------------------------------------------------------
// K3: out = attn_y @ proj_w + proj_b via MFMA. Wave wv owns 32 output cols.
// ---------------------------------------------------------------------------
__global__ __launch_bounds__(256) void k_proj(const float* __restrict__ attn,
                                              const unsigned short* __restrict__ wTp,
                                              const float* __restrict__ proj_b,
                                              float* __restrict__ out) {
    const int tid = threadIdx.x;
    const int lane = tid & 63;
    const int wv = tid >> 6;
    const int pix0 = blockIdx.x * 16;

    __shared__ unsigned short s_y[16 * 128];

    const int n0 = wv * 32;
    const int bn = n0 + (lane & 15);
    const int bk = (lane >> 4) * 8;
    short8v bfrag[8];
    #pragma unroll
    for (int nt = 0; nt < 2; ++nt)
        #pragma unroll
        for (int kk = 0; kk < 4; ++kk)
            bfrag[nt * 4 + kk] =
                *(const short8v*)(wTp + (size_t)(bn + nt * 16) * 128 + kk * 32 + bk);

    const int p = tid >> 4;
    const int c0 = (tid & 15) * 8;
    const float* yp = attn + (size_t)(pix0 + p) * CC + c0;
    const float4v y0 = *(const float4v*)yp;
    const float4v y1 = *(const float4v*)(yp + 4);
    short8v ypack;
    #pragma unroll
    for (int i = 0; i < 4; ++i) ypack[i] = (short)f2bf(y0[i]);
    #pragma unroll
    for (int i = 0; i < 4; ++i) ypack[4 + i] = (short)f2bf(y1[i]);
    {
        int o = p * 256 + (tid & 15) * 16;
        o ^= (p & 7) << 4;
        *(short8v*)((char*)s_y + o) = ypack;
    }
    __syncthreads();

    const int am = lane & 15;
    short8v afr[4];
    #pragma unroll
    for (int kk = 0; kk < 4; ++kk) {
        int o = am * 256 + kk * 64 + (lane >> 4) * 16;
        o ^= (am & 7) << 4;
        afr[kk] = *(const short8v*)((const char*)s_y + o);
    }

    float4v acc[2];
    acc[0] = (float4v){0.f, 0.f, 0.f, 0.f};
    acc[1] = (float4v){0.f, 0.f, 0.f, 0.f};
    #pragma unroll
    for (int nt = 0; nt < 2; ++nt)
        #pragma unroll
        for (int kk = 0; kk < 4; ++kk)
            acc[nt] = __builtin_amdgcn_mfma_f32_16x16x32_bf16(
                afr[kk], bfrag[nt * 4 + kk], acc[nt], 0, 0, 0);

    #pragma unroll
    for (int nt = 0; nt < 2; ++nt) {
        const int n = n0 + nt * 16 + (lane & 15);
        const float bias = proj_b[n];
        #pragma unroll
        for (int jj = 0; jj < 4; ++jj) {
            const int pix = pix0 + (lane >> 4) * 4 + jj;
            out[(size_t)pix * CC + n] = acc[nt][jj] + bias;
        }
    }
}

extern "C" void kernel_launch(void* const* d_in, const int* in_sizes, int n_in,
                              void* d_out, int out_size, void* d_ws, size_t ws_size,
                              hipStream_t stream) {
    const float* x      = (const float*)d_in[0];
    const int*   t      = (const int*)d_in[2];
    const float* ln_w   = (const float*)d_in[3];
    const float* ln_b   = (const float*)d_in[4];
    const float* qkv_w  = (const float*)d_in[5];
    const float* qkv_b  = (const float*)d_in[6];
    const float* rpb    = (const float*)d_in[7];
    const float* proj_w = (const float*)d_in[8];
    const float* proj_b = (const float*)d_in[9];
    float* out = (float*)d_out;

    char* ws = (char*)d_ws;
    float*          ada  = (float*)ws;                       // 2 KB
    unsigned short* wTq  = (unsigned short*)(ws + 2048);     // 96 KB
    unsigned short* wTp  = (unsigned short*)(ws + 2048 + 98304);  // 32 KB
    float*          q    = (float*)(ws + 2048 + 98304 + 32768);
    const size_t QSZ = (size_t)BB * NH * HH * WW * HD;       // 1 M floats
    float* k    = q + QSZ;
    float* v    = k + QSZ;
    float* attn = v + QSZ;

    const int NPIX = BB * HH * WW;  // 8192

    k_prep<<<17, 256, 0, stream>>>(t, ln_w, ln_b, qkv_w, proj_w, ada, wTq, wTp);
    k_lnqkv<<<NPIX / 16, 256, 0, stream>>>(x, ada, wTq, qkv_b, q, k, v);
    k_attn<<<(BB * NH * HH * WW * 8) / 256, 256, 0, stream>>>(q, k, v, rpb, attn);
    k_proj<<<NPIX / 16, 256, 0, stream>>>(attn, wTp, proj_b, out);
}